// Round 1
// 799.509 us; speedup vs baseline: 1.0859x; 1.0859x over previous
//
#include <hip/hip_runtime.h>
#include <cstdint>

// Problem constants: B=256, C=2048, H*W=196, E=16, A=3000
#define BN   256
#define CN   2048
#define HWN  196
#define EN   16
#define AN   3000

// GEMM tile params
#define TS   32            // samples per tile
#define TA   64            // answers per tile
#define KC   32            // K-chunk (floats) staged per iteration = 128 B/row
#define KSPLIT 4           // K-dimension split for occupancy (grid 752 -> 3008 blocks)
#define KPART (CN / KSPLIT)
#define NCHUNK (KPART / KC)   // 16

#define RPW  8             // pool: channel rows per wave

// ---------------------------------------------------------------------------
// global_load_lds helper: async global->LDS DMA, 16 B per lane.
// LDS dest is wave-uniform base + lane*16 (guide §5 caveat).
// ---------------------------------------------------------------------------
typedef const __attribute__((address_space(1))) void gvoid_t;
typedef __attribute__((address_space(3))) void lvoid_t;
__device__ __forceinline__ void gll16(const float* g, float* l) {
    __builtin_amdgcn_global_load_lds((gvoid_t*)g, (lvoid_t*)l, 16, 0, 0);
}

// ---------------------------------------------------------------------------
// Kernel 1: masked weighted pool, denominator fused.
// One wave handles 8 consecutive channel rows of one sample: mask f4 held in
// registers (reused 8x + reduced for the denominator), 9 independent
// butterflies interleaved.
// ---------------------------------------------------------------------------
__global__ __launch_bounds__(256) void pool_kernel(const float* __restrict__ mask,
                                                   const float* __restrict__ feat,
                                                   float* __restrict__ attended) {
    int wave = blockIdx.x * 4 + (threadIdx.x >> 6);
    int lane = threadIdx.x & 63;
    int b  = wave >> 8;               // 2048/RPW = 256 waves per sample
    int c0 = (wave & 255) * RPW;
    bool act = lane < HWN / 4;        // 49 active lanes

    float4 m = make_float4(0.f, 0.f, 0.f, 0.f);
    if (act) {
        m = ((const float4*)(mask + (size_t)b * HWN))[lane];
        m.x += 1e-10f; m.y += 1e-10f; m.z += 1e-10f; m.w += 1e-10f;
    }
    const float4* fb = (const float4*)(feat + ((size_t)b * CN + c0) * HWN);
    float4 f[RPW];
    #pragma unroll
    for (int r = 0; r < RPW; r++)
        f[r] = act ? fb[r * (HWN / 4) + lane] : make_float4(0.f, 0.f, 0.f, 0.f);

    float red[RPW + 1];
    #pragma unroll
    for (int r = 0; r < RPW; r++)
        red[r] = m.x * f[r].x + m.y * f[r].y + m.z * f[r].z + m.w * f[r].w;
    red[RPW] = m.x + m.y + m.z + m.w;   // denominator partial (eps already added)

    #pragma unroll
    for (int off = 32; off; off >>= 1)
        #pragma unroll
        for (int r = 0; r <= RPW; r++) red[r] += __shfl_xor(red[r], off, 64);

    if (lane == 0) {
        float rd = 1.0f / red[RPW];
        float4 o0 = make_float4(red[0] * rd, red[1] * rd, red[2] * rd, red[3] * rd);
        float4 o1 = make_float4(red[4] * rd, red[5] * rd, red[6] * rd, red[7] * rd);
        float4* orow = (float4*)(attended + (size_t)b * CN + c0);
        orow[0] = o0; orow[1] = o1;
    }
}

// ---------------------------------------------------------------------------
// Kernel 2: out[b,:] = bias[inst[b],:]; block 0 additionally groups samples
// by expert (independent work, saves a launch).
// ---------------------------------------------------------------------------
__global__ __launch_bounds__(256) void bias_group_kernel(const float* __restrict__ bias,
                                                         const int* __restrict__ inst,
                                                         float* __restrict__ out,
                                                         int* __restrict__ counts,
                                                         int* __restrict__ lists) {
    int b = blockIdx.x;
    int e = inst[b];
    const float4* br = (const float4*)(bias + (size_t)e * AN);
    float4* orow = (float4*)(out + (size_t)b * AN);
    for (int j = threadIdx.x; j < AN / 4; j += 256) orow[j] = br[j];

    if (blockIdx.x == 0) {
        __shared__ int cnt[EN];
        int t = threadIdx.x;
        if (t < EN) cnt[t] = 0;
        __syncthreads();
        if (t < BN) {
            int ee = inst[t];
            int pos = atomicAdd(&cnt[ee], 1);
            lists[ee * BN + pos] = t;
        }
        __syncthreads();
        if (t < EN) counts[t] = cnt[t];
    }
}

// ---------------------------------------------------------------------------
// Kernel 3: grouped expert GEMM, K-split, global_load_lds double-buffered.
//
// LDS tile: [96 rows][32 floats] unpadded (A rows 0..31 = samples, W rows
// 32..95 = answers). Staged in 12 x 1KB wave-units (8 rows each) via
// global_load_lds; bank conflicts avoided by XOR swizzle (both sides,
// rule #21): stage lane (r,c) fetches global 16B-segment c^r of row r;
// reader wanting segment kc of row R reads slot kc^(R&7). Per wave-read:
// 8 distinct slots -> 32 distinct banks -> conflict-free.
//
// Schedule (T3 minimum): stage next chunk -> ds_read+FMA cur -> syncthreads
// (its vmcnt(0) drain happens AFTER ~1000cy of FMA -> short). 1 barrier/chunk.
// ---------------------------------------------------------------------------
__global__ __launch_bounds__(128, 3) void gemm_kernel(const float* __restrict__ attended,
                                                      const float* __restrict__ W,
                                                      const int* __restrict__ counts,
                                                      const int* __restrict__ lists,
                                                      float* __restrict__ out) {
    int e  = blockIdx.y;
    int kp = blockIdx.z;
    int a0 = blockIdx.x * TA;
    int n  = counts[e];
    if (n == 0) return;
    int kbeg = kp * KPART;

    __shared__ __align__(16) float tile[2][(TS + TA) * KC];   // 2 x 12 KB
    __shared__ int sid[TS];

    int t    = threadIdx.x;
    int ts   = t & 7;         // sample group (rows ts+8i)
    int ta   = t >> 3;        // answer group 0..15 (rows ta+16j)
    int wv_  = t >> 6;        // wave id 0/1
    int lane = t & 63;
    int r    = lane >> 3;     // row within 8-row stage unit
    int cs   = (lane & 7) ^ r;  // pre-swizzled global segment index

    const int* lst = lists + e * BN;

    for (int s0 = 0; s0 < n; s0 += TS) {
        if (t < TS) sid[t] = (s0 + t < n) ? lst[s0 + t] : -1;
        __syncthreads();   // sid visible

        // per-thread stage source pointers (fixed across the k-loop)
        const float* gsrc[6];
        #pragma unroll
        for (int q = 0; q < 6; q++) {
            int u = wv_ * 6 + q;                 // stage unit 0..11
            if (u < 4) {                         // A units: tile rows 8u..8u+7
                int s = sid[8 * u + r];
                if (s < 0) s = sid[0];           // pad rows read a valid row; acc discarded
                gsrc[q] = attended + (size_t)s * CN + kbeg + cs * 4;
            } else {                             // W units: answer rows 8(u-4)..+7
                int a = a0 + 8 * (u - 4) + r;
                if (a > AN - 1) a = AN - 1;      // clamp, result discarded
                gsrc[q] = W + ((size_t)e * AN + a) * CN + kbeg + cs * 4;
            }
        }

        float acc[4][4];
        #pragma unroll
        for (int i = 0; i < 4; i++)
            #pragma unroll
            for (int j = 0; j < 4; j++) acc[i][j] = 0.f;

        // prologue: stage chunk 0 into buf 0
        #pragma unroll
        for (int q = 0; q < 6; q++)
            gll16(gsrc[q], &tile[0][(wv_ * 6 + q) * 256]);
        __syncthreads();   // drain DMA + barrier

        int cur = 0;
        for (int ck = 0; ck < NCHUNK; ck++) {
            // issue next chunk's DMA before computing current
            if (ck + 1 < NCHUNK) {
                #pragma unroll
                for (int q = 0; q < 6; q++)
                    gll16(gsrc[q] + (ck + 1) * KC, &tile[cur ^ 1][(wv_ * 6 + q) * 256]);
            }

            const float* tb = tile[cur];
            #pragma unroll
            for (int kc = 0; kc < KC / 4; kc++) {
                float4 av[4], wvv[4];
                #pragma unroll
                for (int i = 0; i < 4; i++)
                    av[i] = *(const float4*)(tb + (ts + 8 * i) * KC + ((kc ^ ts) << 2));
                #pragma unroll
                for (int j = 0; j < 4; j++)
                    wvv[j] = *(const float4*)(tb + (TS + ta + 16 * j) * KC + ((kc ^ (ta & 7)) << 2));
                #pragma unroll
                for (int i = 0; i < 4; i++)
                    #pragma unroll
                    for (int j = 0; j < 4; j++) {
                        acc[i][j] += av[i].x * wvv[j].x;
                        acc[i][j] += av[i].y * wvv[j].y;
                        acc[i][j] += av[i].z * wvv[j].z;
                        acc[i][j] += av[i].w * wvv[j].w;
                    }
            }
            __syncthreads();   // drains this iter's DMA (landed under FMA) + barrier
            cur ^= 1;
        }

        // epilogue: accumulate K-split partial into bias-initialized out
        #pragma unroll
        for (int j = 0; j < 4; j++) {
            int a = a0 + ta + 16 * j;
            if (a < AN) {
                #pragma unroll
                for (int i = 0; i < 4; i++) {
                    int s = sid[ts + 8 * i];
                    if (s >= 0) atomicAdd(&out[(size_t)s * AN + a], acc[i][j]);
                }
            }
        }
        __syncthreads();   // sid/LDS reused next tile
    }
}

// ---------------------------------------------------------------------------
extern "C" void kernel_launch(void* const* d_in, const int* in_sizes, int n_in,
                              void* d_out, int out_size, void* d_ws, size_t ws_size,
                              hipStream_t stream) {
    const float* mask = (const float*)d_in[0];
    const float* feat = (const float*)d_in[1];
    const float* W    = (const float*)d_in[2];
    const float* bias = (const float*)d_in[3];
    const int*   inst = (const int*)d_in[4];
    float* out = (float*)d_out;

    char* ws = (char*)d_ws;
    float* attended = (float*)ws;                                  // 2 MB
    int*   counts   = (int*)(ws + (size_t)BN * CN * sizeof(float));
    int*   lists    = counts + EN;

    // 0) out = bias[inst[b]]; block 0 also groups samples by expert
    bias_group_kernel<<<BN, 256, 0, stream>>>(bias, inst, out, counts, lists);
    // 1) masked pool + fused denominator (8 rows/wave)
    pool_kernel<<<BN * CN / RPW / 4, 256, 0, stream>>>(mask, feat, attended);
    // 2) grouped GEMM, K-split x4, atomic accumulate
    dim3 grid((AN + TA - 1) / TA, EN, KSPLIT);
    gemm_kernel<<<grid, 128, 0, stream>>>(attended, W, counts, lists, out);
}

// Round 2
// 797.052 us; speedup vs baseline: 1.0892x; 1.0031x over previous
//
#include <hip/hip_runtime.h>
#include <cstdint>

// Problem constants: B=256, C=2048, H*W=196, E=16, A=3000
#define BN   256
#define CN   2048
#define HWN  196
#define EN   16
#define AN   3000

// GEMM tile params
#define TS   32            // samples per tile
#define TA   64            // answers per tile
#define KC   32            // K-chunk (floats) staged per iteration = 128 B/row
#define KSPLIT 2           // K-split: grid 47*16*2=1504 ~= 5.9 blocks/CU = ONE
                           // residency generation (LDS caps 6/CU); halves atomic
                           // RMW traffic vs KSPLIT=4 (R1: 24->12 MB, 6.2M->3.1M atomics)
#define KPART (CN / KSPLIT)
#define NCHUNK (KPART / KC)   // 32

#define RPW  8             // pool: channel rows per wave

// ---------------------------------------------------------------------------
// global_load_lds helper: async global->LDS DMA, 16 B per lane.
// LDS dest is wave-uniform base + lane*16 (guide §5 caveat).
// ---------------------------------------------------------------------------
typedef const __attribute__((address_space(1))) void gvoid_t;
typedef __attribute__((address_space(3))) void lvoid_t;
__device__ __forceinline__ void gll16(const float* g, float* l) {
    __builtin_amdgcn_global_load_lds((gvoid_t*)g, (lvoid_t*)l, 16, 0, 0);
}

// ---------------------------------------------------------------------------
// Kernel 1: masked weighted pool, denominator fused.
// One wave handles 8 consecutive channel rows of one sample: mask f4 held in
// registers (reused 8x + reduced for the denominator), 9 independent
// butterflies interleaved. BW-bound: 411 MB features @ ~6.3 TB/s ~= 68 us.
// ---------------------------------------------------------------------------
__global__ __launch_bounds__(256) void pool_kernel(const float* __restrict__ mask,
                                                   const float* __restrict__ feat,
                                                   float* __restrict__ attended) {
    int wave = blockIdx.x * 4 + (threadIdx.x >> 6);
    int lane = threadIdx.x & 63;
    int b  = wave >> 8;               // 2048/RPW = 256 waves per sample
    int c0 = (wave & 255) * RPW;
    bool act = lane < HWN / 4;        // 49 active lanes

    float4 m = make_float4(0.f, 0.f, 0.f, 0.f);
    if (act) {
        m = ((const float4*)(mask + (size_t)b * HWN))[lane];
        m.x += 1e-10f; m.y += 1e-10f; m.z += 1e-10f; m.w += 1e-10f;
    }
    const float4* fb = (const float4*)(feat + ((size_t)b * CN + c0) * HWN);
    float4 f[RPW];
    #pragma unroll
    for (int r = 0; r < RPW; r++)
        f[r] = act ? fb[r * (HWN / 4) + lane] : make_float4(0.f, 0.f, 0.f, 0.f);

    float red[RPW + 1];
    #pragma unroll
    for (int r = 0; r < RPW; r++)
        red[r] = m.x * f[r].x + m.y * f[r].y + m.z * f[r].z + m.w * f[r].w;
    red[RPW] = m.x + m.y + m.z + m.w;   // denominator partial (eps already added)

    #pragma unroll
    for (int off = 32; off; off >>= 1)
        #pragma unroll
        for (int r = 0; r <= RPW; r++) red[r] += __shfl_xor(red[r], off, 64);

    if (lane == 0) {
        float rd = 1.0f / red[RPW];
        float4 o0 = make_float4(red[0] * rd, red[1] * rd, red[2] * rd, red[3] * rd);
        float4 o1 = make_float4(red[4] * rd, red[5] * rd, red[6] * rd, red[7] * rd);
        float4* orow = (float4*)(attended + (size_t)b * CN + c0);
        orow[0] = o0; orow[1] = o1;
    }
}

// ---------------------------------------------------------------------------
// Kernel 2: out[b,:] = bias[inst[b],:]; block 0 additionally groups samples
// by expert (independent work, saves a launch).
// ---------------------------------------------------------------------------
__global__ __launch_bounds__(256) void bias_group_kernel(const float* __restrict__ bias,
                                                         const int* __restrict__ inst,
                                                         float* __restrict__ out,
                                                         int* __restrict__ counts,
                                                         int* __restrict__ lists) {
    int b = blockIdx.x;
    int e = inst[b];
    const float4* br = (const float4*)(bias + (size_t)e * AN);
    float4* orow = (float4*)(out + (size_t)b * AN);
    for (int j = threadIdx.x; j < AN / 4; j += 256) orow[j] = br[j];

    if (blockIdx.x == 0) {
        __shared__ int cnt[EN];
        int t = threadIdx.x;
        if (t < EN) cnt[t] = 0;
        __syncthreads();
        if (t < BN) {
            int ee = inst[t];
            int pos = atomicAdd(&cnt[ee], 1);
            lists[ee * BN + pos] = t;
        }
        __syncthreads();
        if (t < EN) counts[t] = cnt[t];
    }
}

// ---------------------------------------------------------------------------
// Kernel 3: grouped expert GEMM, K-split x2, global_load_lds double-buffered.
//
// LDS tile: [96 rows][32 floats] unpadded (A rows 0..31 = samples, W rows
// 32..95 = answers). Staged in 12 x 1KB wave-units (8 rows each) via
// global_load_lds; bank conflicts avoided by XOR swizzle (both sides,
// rule #21): stage lane (r,c) fetches global 16B-segment c^r of row r;
// reader wanting segment kc of row R reads slot kc^(R&7). Per wave-read:
// 8 distinct slots -> 32 distinct banks -> conflict-free (R1: 0 conflicts).
//
// Schedule (T3 minimum): stage next chunk -> ds_read+FMA cur -> syncthreads.
// The per-block vmcnt(0) drain at the barrier is hidden by the ~6 independent
// co-resident blocks/CU destaggering their phases; W stream (393 MB read
// exactly once) saturates HBM -> ~65 us floor.
// ---------------------------------------------------------------------------
__global__ __launch_bounds__(128, 3) void gemm_kernel(const float* __restrict__ attended,
                                                      const float* __restrict__ W,
                                                      const int* __restrict__ counts,
                                                      const int* __restrict__ lists,
                                                      float* __restrict__ out) {
    int e  = blockIdx.y;
    int kp = blockIdx.z;
    int a0 = blockIdx.x * TA;
    int n  = counts[e];
    if (n == 0) return;
    int kbeg = kp * KPART;

    __shared__ __align__(16) float tile[2][(TS + TA) * KC];   // 2 x 12 KB
    __shared__ int sid[TS];

    int t    = threadIdx.x;
    int ts   = t & 7;         // sample group (rows ts+8i)
    int ta   = t >> 3;        // answer group 0..15 (rows ta+16j)
    int wv_  = t >> 6;        // wave id 0/1
    int lane = t & 63;
    int r    = lane >> 3;     // row within 8-row stage unit
    int cs   = (lane & 7) ^ r;  // pre-swizzled global segment index

    const int* lst = lists + e * BN;

    for (int s0 = 0; s0 < n; s0 += TS) {
        if (t < TS) sid[t] = (s0 + t < n) ? lst[s0 + t] : -1;
        __syncthreads();   // sid visible

        // per-thread stage source pointers (fixed across the k-loop)
        const float* gsrc[6];
        #pragma unroll
        for (int q = 0; q < 6; q++) {
            int u = wv_ * 6 + q;                 // stage unit 0..11
            if (u < 4) {                         // A units: tile rows 8u..8u+7
                int s = sid[8 * u + r];
                if (s < 0) s = sid[0];           // pad rows read a valid row; acc discarded
                gsrc[q] = attended + (size_t)s * CN + kbeg + cs * 4;
            } else {                             // W units: answer rows 8(u-4)..+7
                int a = a0 + 8 * (u - 4) + r;
                if (a > AN - 1) a = AN - 1;      // clamp, result discarded
                gsrc[q] = W + ((size_t)e * AN + a) * CN + kbeg + cs * 4;
            }
        }

        float acc[4][4];
        #pragma unroll
        for (int i = 0; i < 4; i++)
            #pragma unroll
            for (int j = 0; j < 4; j++) acc[i][j] = 0.f;

        // prologue: stage chunk 0 into buf 0
        #pragma unroll
        for (int q = 0; q < 6; q++)
            gll16(gsrc[q], &tile[0][(wv_ * 6 + q) * 256]);
        __syncthreads();   // drain DMA + barrier

        int cur = 0;
        for (int ck = 0; ck < NCHUNK; ck++) {
            // issue next chunk's DMA before computing current
            if (ck + 1 < NCHUNK) {
                #pragma unroll
                for (int q = 0; q < 6; q++)
                    gll16(gsrc[q] + (ck + 1) * KC, &tile[cur ^ 1][(wv_ * 6 + q) * 256]);
            }

            const float* tb = tile[cur];
            #pragma unroll
            for (int kc = 0; kc < KC / 4; kc++) {
                float4 av[4], wvv[4];
                #pragma unroll
                for (int i = 0; i < 4; i++)
                    av[i] = *(const float4*)(tb + (ts + 8 * i) * KC + ((kc ^ ts) << 2));
                #pragma unroll
                for (int j = 0; j < 4; j++)
                    wvv[j] = *(const float4*)(tb + (TS + ta + 16 * j) * KC + ((kc ^ (ta & 7)) << 2));
                #pragma unroll
                for (int i = 0; i < 4; i++)
                    #pragma unroll
                    for (int j = 0; j < 4; j++) {
                        acc[i][j] += av[i].x * wvv[j].x;
                        acc[i][j] += av[i].y * wvv[j].y;
                        acc[i][j] += av[i].z * wvv[j].z;
                        acc[i][j] += av[i].w * wvv[j].w;
                    }
            }
            __syncthreads();   // drains this iter's DMA (landed under FMA) + barrier
            cur ^= 1;
        }

        // epilogue: accumulate K-split partial into bias-initialized out
        #pragma unroll
        for (int j = 0; j < 4; j++) {
            int a = a0 + ta + 16 * j;
            if (a < AN) {
                #pragma unroll
                for (int i = 0; i < 4; i++) {
                    int s = sid[ts + 8 * i];
                    if (s >= 0) atomicAdd(&out[(size_t)s * AN + a], acc[i][j]);
                }
            }
        }
        __syncthreads();   // sid/LDS reused next tile
    }
}

// ---------------------------------------------------------------------------
extern "C" void kernel_launch(void* const* d_in, const int* in_sizes, int n_in,
                              void* d_out, int out_size, void* d_ws, size_t ws_size,
                              hipStream_t stream) {
    const float* mask = (const float*)d_in[0];
    const float* feat = (const float*)d_in[1];
    const float* W    = (const float*)d_in[2];
    const float* bias = (const float*)d_in[3];
    const int*   inst = (const int*)d_in[4];
    float* out = (float*)d_out;

    char* ws = (char*)d_ws;
    float* attended = (float*)ws;                                  // 2 MB
    int*   counts   = (int*)(ws + (size_t)BN * CN * sizeof(float));
    int*   lists    = counts + EN;

    // 0) out = bias[inst[b]]; block 0 also groups samples by expert
    bias_group_kernel<<<BN, 256, 0, stream>>>(bias, inst, out, counts, lists);
    // 1) masked pool + fused denominator (8 rows/wave)
    pool_kernel<<<BN * CN / RPW / 4, 256, 0, stream>>>(mask, feat, attended);
    // 2) grouped GEMM, K-split x2, atomic accumulate
    dim3 grid((AN + TA - 1) / TA, EN, KSPLIT);
    gemm_kernel<<<grid, 128, 0, stream>>>(attended, W, counts, lists, out);
}